// Round 9
// baseline (2131.346 us; speedup 1.0000x reference)
//
#include <hip/hip_runtime.h>
#include <cstdint>
#include <cstddef>

// B=4, I=128, N=128 (127+super), D=128, H=4, DK=16, L=4, FFN=32
// ws layout (floats): X[8388608] Q1 K1 V1 Q2 K2 V2 [4194304 each] YC[8388608]
// All Q/K/V tensors share layout [(b*128+i)*4 + h][n*16 + u] (round-2 fix).
// Attention: 4 lanes per row (round-7 fix), 32 scores/thread, quad shfl
// reductions. sK/sV [128][16] with col^((j>>5)<<2) XOR swizzle: the 4 j's
// read per wave instr (j+32m) always share a bank group for ANY row stride;
// XOR spreads them to 4 disjoint groups (16-lane broadcast each).
// launch_bounds(512,4): cap 128 VGPR -> 2 blocks/CU (round-8 tightening).
// k_qkv: encoder-split + per-buffer swizzle (round-6).

__device__ __forceinline__ int swz (int r, int c){ return c ^ (((r >> 2) & 7) << 2); }
__device__ __forceinline__ int swzA(int r, int c){ return c ^ ((r & 7) << 2); }

// ---------------------------------------------------------------- build x0
__global__ __launch_bounds__(256) void k_build_x(const float4* __restrict__ ne,
    const float4* __restrict__ hts, const float4* __restrict__ sup,
    float4* __restrict__ X){
  int idx = blockIdx.x * 256 + threadIdx.x;      // 2097152 float4s
  int d4 = idx & 31;
  int n  = (idx >> 5) & 127;
  int bi = idx >> 12;
  float4 v;
  if (n == 0){
    v = sup[d4];
  } else {
    size_t s = ((size_t)bi * 127 + (n - 1)) * 32 + d4;
    float4 a = ne[s], h = hts[s];
    v.x = a.x + h.x; v.y = a.y + h.y; v.z = a.z + h.z; v.w = a.w + h.w;
  }
  X[idx] = v;
}

// ---------------------------------------------------------------- LN + QKV (one encoder per block.y)
struct QkvArgs {
  const float* x;
  const float* ln_g[2]; const float* ln_b[2];
  const float* w[6];  const float* wb[6];
  float* out[6];   // all: [(b*128+i)*4 + h][n*16 + u]
};

__global__ __launch_bounds__(256, 3) void k_qkv(QkvArgs A){
  __shared__ float sY[32 * 128];    // this encoder's LN'd rows (swzA layout)
  __shared__ float sW[64 * 128];    // current W tile (swz layout)
  const int r0  = blockIdx.x * 32;
  const int enc = blockIdx.y;       // 0 or 1
  const int t   = threadIdx.x;
  // ---- stage raw X tile (32 rows x 128)
  {
    const float4* xs = (const float4*)(A.x + (size_t)r0 * 128);
    #pragma unroll
    for (int it = 0; it < 4; ++it){
      int el = it * 256 + t;                 // 0..1023
      int rr = el >> 5, c4 = (el & 31) * 4;
      *(float4*)&sY[rr * 128 + swzA(rr, c4)] = xs[el];
    }
  }
  __syncthreads();
  // ---- LN: 8 threads per row, contiguous 16-float slices
  const int row = t >> 3, part = t & 7;
  float s1 = 0.f, s2 = 0.f;
  float4 xv[4];
  #pragma unroll
  for (int q = 0; q < 4; ++q){
    int c4 = part * 16 + q * 4;
    xv[q] = *(const float4*)&sY[row * 128 + swzA(row, c4)];
    s1 += xv[q].x + xv[q].y + xv[q].z + xv[q].w;
    s2 += xv[q].x*xv[q].x + xv[q].y*xv[q].y + xv[q].z*xv[q].z + xv[q].w*xv[q].w;
  }
  s1 += __shfl_xor(s1, 1); s2 += __shfl_xor(s2, 1);
  s1 += __shfl_xor(s1, 2); s2 += __shfl_xor(s2, 2);
  s1 += __shfl_xor(s1, 4); s2 += __shfl_xor(s2, 4);
  float mean = s1 * (1.f / 128.f);
  float rstd = rsqrtf(s2 * (1.f / 128.f) - mean * mean + 1e-5f);
  {
    const float* lg = A.ln_g[enc];
    const float* lb = A.ln_b[enc];
    #pragma unroll
    for (int q = 0; q < 4; ++q){
      int cc = part * 16 + q * 4;
      int a  = row * 128 + swzA(row, cc);
      float4 gv = *(const float4*)&lg[cc];
      float4 bv = *(const float4*)&lb[cc];
      float4 y;
      y.x = (xv[q].x - mean) * rstd * gv.x + bv.x;
      y.y = (xv[q].y - mean) * rstd * gv.y + bv.y;
      y.z = (xv[q].z - mean) * rstd * gv.z + bv.z;
      y.w = (xv[q].w - mean) * rstd * gv.w + bv.w;
      *(float4*)&sY[a] = y;
    }
  }
  // ---- 3 GEMMs: 32x64x128 each; thread = 2 rows x 4 cols
  const int tc = t & 15, tr = t >> 4;
  const int kb_x  = (tc & 7) << 2;           // sW swizzle: W rows tc*4..+3 share (r>>2)
  const int ra0 = tr * 2, ra1 = tr * 2 + 1;
  const int ka_x0 = (ra0 & 7) << 2;          // sY swizzle: per-row -> A-reads conflict-free
  const int ka_x1 = (ra1 & 7) << 2;
  for (int g3 = 0; g3 < 3; ++g3){
    const int g = enc * 3 + g3;
    __syncthreads();                          // prev compute / LN done before sW overwrite
    {
      const float4* wsrc = (const float4*)A.w[g];
      #pragma unroll
      for (int it = 0; it < 8; ++it){
        int el = it * 256 + t;                // 0..2047
        int rr = el >> 5, c4 = (el & 31) * 4;
        *(float4*)&sW[rr * 128 + swz(rr, c4)] = wsrc[el];
      }
    }
    __syncthreads();
    float acc[2][4] = {};
    #pragma unroll
    for (int k = 0; k < 128; k += 4){
      float4 av[2], bv[4];
      av[0] = *(const float4*)&sY[ra0 * 128 + (k ^ ka_x0)];
      av[1] = *(const float4*)&sY[ra1 * 128 + (k ^ ka_x1)];
      int kb = k ^ kb_x;
      #pragma unroll
      for (int q = 0; q < 4; ++q) bv[q] = *(const float4*)&sW[(tc * 4 + q) * 128 + kb];
      #pragma unroll
      for (int i2 = 0; i2 < 2; ++i2)
        #pragma unroll
        for (int j2 = 0; j2 < 4; ++j2){
          acc[i2][j2] += av[i2].x * bv[j2].x;
          acc[i2][j2] += av[i2].y * bv[j2].y;
          acc[i2][j2] += av[i2].z * bv[j2].z;
          acc[i2][j2] += av[i2].w * bv[j2].w;
        }
    }
    const float scale = (g3 == 0) ? 0.25f : 1.0f;   // SCALE = DK^-0.5 on Q only
    const float* wb = A.wb[g];
    const float b0 = wb[tc*4], b1 = wb[tc*4+1], b2 = wb[tc*4+2], b3 = wb[tc*4+3];
    float* outp = A.out[g];
    const int h_ = tc >> 2, u_ = (tc & 3) * 4;
    #pragma unroll
    for (int i2 = 0; i2 < 2; ++i2){
      int gr = r0 + tr * 2 + i2;              // ((b*128+i)*128+n)
      size_t off = ((size_t)((gr >> 7) * 4 + h_)) * 2048 + (gr & 127) * 16 + u_;
      float4 o;
      o.x = (acc[i2][0] + b0) * scale;
      o.y = (acc[i2][1] + b1) * scale;
      o.z = (acc[i2][2] + b2) * scale;
      o.w = (acc[i2][3] + b3) * scale;
      *(float4*)&outp[off] = o;
    }
  }
}

// ---------------------------------------------------------------- attention, index stream (enc1)
// 4 lanes per row: thread (i = t>>2, qd = t&3) owns scores j in [qd*32, qd*32+32).
__global__ __launch_bounds__(512, 4) void k_attn1(const float* __restrict__ Q,
    const float* __restrict__ K, const float* __restrict__ V,
    const float* __restrict__ iab, float* __restrict__ YC){
  __shared__ float sK[128][16];
  __shared__ float sV[128][16];
  const int seq = blockIdx.x;    // b*128 + n
  const int h   = blockIdx.y;
  const int t   = threadIdx.x;
  const int i   = t >> 2, qd = t & 3;
  const int b_ = seq >> 7, n_ = seq & 127;
  const size_t rbase = ((size_t)((b_ * 128 + i) * 4 + h)) * 2048 + n_ * 16;
  // stage K/V: one float4 per thread, XOR-swizzled column
  {
    int swc = (qd * 4) ^ ((i >> 5) << 2);
    *(float4*)&sK[i][swc] = *(const float4*)&K[rbase + qd * 4];
    *(float4*)&sV[i][swc] = *(const float4*)&V[rbase + qd * 4];
  }
  float q[16];
  #pragma unroll
  for (int u = 0; u < 4; ++u){
    float4 v = *(const float4*)&Q[rbase + u * 4];
    q[u*4+0] = v.x; q[u*4+1] = v.y; q[u*4+2] = v.z; q[u*4+3] = v.w;
  }
  __syncthreads();
  const float4* brow = (const float4*)(iab + (size_t)seq * 16384 + (size_t)i * 128 + qd * 32);
  const int jsw = qd << 2;                   // (j>>5)<<2 for j = qd*32+jj
  float s[32];
  #pragma unroll
  for (int j8 = 0; j8 < 8; ++j8){
    float4 bv4 = brow[j8];
    float bb[4] = {bv4.x, bv4.y, bv4.z, bv4.w};
    #pragma unroll
    for (int u = 0; u < 4; ++u){
      int jj = j8 * 4 + u;
      int j  = qd * 32 + jj;
      float acc = bb[u];
      #pragma unroll
      for (int u4 = 0; u4 < 4; ++u4){
        float4 kv = *(const float4*)&sK[j][(u4 * 4) ^ jsw];
        acc += q[u4*4+0]*kv.x + q[u4*4+1]*kv.y + q[u4*4+2]*kv.z + q[u4*4+3]*kv.w;
      }
      s[jj] = acc;
    }
  }
  float m = -1e30f;
  #pragma unroll
  for (int jj = 0; jj < 32; ++jj) m = fmaxf(m, s[jj]);
  m = fmaxf(m, __shfl_xor(m, 1));
  m = fmaxf(m, __shfl_xor(m, 2));
  float sum = 0.f;
  #pragma unroll
  for (int jj = 0; jj < 32; ++jj){ float ev = __expf(s[jj] - m); s[jj] = ev; sum += ev; }
  sum += __shfl_xor(sum, 1);
  sum += __shfl_xor(sum, 2);
  float inv = 1.f / sum;
  float o[16] = {};
  #pragma unroll
  for (int jj = 0; jj < 32; ++jj){
    int j = qd * 32 + jj;
    float p = s[jj];
    #pragma unroll
    for (int u4 = 0; u4 < 4; ++u4){
      float4 vv = *(const float4*)&sV[j][(u4 * 4) ^ jsw];
      o[u4*4+0] += p * vv.x; o[u4*4+1] += p * vv.y;
      o[u4*4+2] += p * vv.z; o[u4*4+3] += p * vv.w;
    }
  }
  #pragma unroll
  for (int e = 0; e < 16; ++e){
    o[e] += __shfl_xor(o[e], 1);
    o[e] += __shfl_xor(o[e], 2);
  }
  // y1 -> YC[b][i][n][h*16 + qd*4 ..]  (channels 0..63)
  size_t off = (((size_t)(b_ * 128 + i)) * 128 + n_) * 128 + h * 16 + qd * 4;
  float4 v;
  v.x = o[qd*4+0]*inv; v.y = o[qd*4+1]*inv; v.z = o[qd*4+2]*inv; v.w = o[qd*4+3]*inv;
  *(float4*)&YC[off] = v;
}

// ---------------------------------------------------------------- attention, node stream (enc2)
__global__ __launch_bounds__(512, 4) void k_attn2(const float* __restrict__ Q,
    const float* __restrict__ K, const float* __restrict__ V,
    const float* __restrict__ tree, const int* __restrict__ mat,
    const float* __restrict__ relemb, const float* __restrict__ sdist,
    float* __restrict__ YC){
  __shared__ float sK[128][16];
  __shared__ float sV[128][16];
  __shared__ float srel[768];          // [192][4]
  const int seq = blockIdx.x;    // b*128 + i (index)
  const int h   = blockIdx.y;
  const int t   = threadIdx.x;
  const int i   = t >> 2, qd = t & 3;  // i = node row
  const size_t base = ((size_t)(seq * 4 + h)) * 2048;
  {
    int swc = (qd * 4) ^ ((i >> 5) << 2);
    *(float4*)&sK[i][swc] = *(const float4*)&K[base + i * 16 + qd * 4];
    *(float4*)&sV[i][swc] = *(const float4*)&V[base + i * 16 + qd * 4];
  }
  float q[16];
  #pragma unroll
  for (int u = 0; u < 4; ++u){
    float4 v = *(const float4*)&Q[base + i * 16 + u * 4];
    q[u*4+0] = v.x; q[u*4+1] = v.y; q[u*4+2] = v.z; q[u*4+3] = v.w;
  }
  for (int u = t; u < 768; u += 512) srel[u] = relemb[u];
  const float tsup = sdist[h];
  __syncthreads();
  const float4* trow = (const float4*)(tree + (size_t)seq * 16384 + (size_t)i * 128 + qd * 32);
  const int4*   mrow = (const int4*)(mat + (size_t)seq * 16384 + (size_t)i * 128 + qd * 32);
  const int jsw = qd << 2;
  float s[32];
  #pragma unroll
  for (int j8 = 0; j8 < 8; ++j8){
    float4 tv = trow[j8];
    int4  mv  = mrow[j8];
    float bb[4];
    bb[0] = tv.x + srel[mv.x * 4 + h];
    bb[1] = tv.y + srel[mv.y * 4 + h];
    bb[2] = tv.z + srel[mv.z * 4 + h];
    bb[3] = tv.w + srel[mv.w * 4 + h];
    #pragma unroll
    for (int u = 0; u < 4; ++u){
      int jj = j8 * 4 + u;
      int j  = qd * 32 + jj;
      float acc = bb[u];
      if (i == 0) acc += tsup;               // tab[:, :, 0, :] += t
      else if (j == 0) acc += tsup;          // tab[:, :, 1:, 0] += t
      #pragma unroll
      for (int u4 = 0; u4 < 4; ++u4){
        float4 kv = *(const float4*)&sK[j][(u4 * 4) ^ jsw];
        acc += q[u4*4+0]*kv.x + q[u4*4+1]*kv.y + q[u4*4+2]*kv.z + q[u4*4+3]*kv.w;
      }
      s[jj] = acc;
    }
  }
  float m = -1e30f;
  #pragma unroll
  for (int jj = 0; jj < 32; ++jj) m = fmaxf(m, s[jj]);
  m = fmaxf(m, __shfl_xor(m, 1));
  m = fmaxf(m, __shfl_xor(m, 2));
  float sum = 0.f;
  #pragma unroll
  for (int jj = 0; jj < 32; ++jj){ float ev = __expf(s[jj] - m); s[jj] = ev; sum += ev; }
  sum += __shfl_xor(sum, 1);
  sum += __shfl_xor(sum, 2);
  float inv = 1.f / sum;
  float o[16] = {};
  #pragma unroll
  for (int jj = 0; jj < 32; ++jj){
    int j = qd * 32 + jj;
    float p = s[jj];
    #pragma unroll
    for (int u4 = 0; u4 < 4; ++u4){
      float4 vv = *(const float4*)&sV[j][(u4 * 4) ^ jsw];
      o[u4*4+0] += p * vv.x; o[u4*4+1] += p * vv.y;
      o[u4*4+2] += p * vv.z; o[u4*4+3] += p * vv.w;
    }
  }
  #pragma unroll
  for (int e = 0; e < 16; ++e){
    o[e] += __shfl_xor(o[e], 1);
    o[e] += __shfl_xor(o[e], 2);
  }
  // y2 -> YC[b][i_index][n][64 + h*16 + qd*4 ..]
  size_t off = (((size_t)seq) * 128 + i) * 128 + 64 + h * 16 + qd * 4;
  float4 v;
  v.x = o[qd*4+0]*inv; v.y = o[qd*4+1]*inv; v.z = o[qd*4+2]*inv; v.w = o[qd*4+3]*inv;
  *(float4*)&YC[off] = v;
}

// ---------------------------------------------------------------- attn out-proj + residual
__global__ __launch_bounds__(256, 2) void k_attn_out(const float* __restrict__ YC,
    const float* __restrict__ W, const float* __restrict__ bias, float* __restrict__ X){
  __shared__ float sA[64 * 128];
  __shared__ float sW[64 * 128];
  const int r0 = blockIdx.x * 64, c0 = blockIdx.y * 64;
  const int t  = threadIdx.x;
  {
    const float4* as   = (const float4*)(YC + (size_t)r0 * 128);
    const float4* wsrc = (const float4*)(W + (size_t)c0 * 128);
    #pragma unroll
    for (int it = 0; it < 8; ++it){
      int e  = it * 256 + t;
      int rr = e >> 5, c4 = (e & 31) * 4;
      int cs = swz(rr, c4);
      *(float4*)&sA[rr * 128 + cs] = as[e];
      *(float4*)&sW[rr * 128 + cs] = wsrc[e];
    }
  }
  __syncthreads();
  const int tc = t & 15, tr = t >> 4;
  float acc[4][4] = {};
  #pragma unroll
  for (int k = 0; k < 128; k += 4){
    float4 av[4], bv[4];
    int ka = k ^ ((tr & 7) << 2);
    int kb = k ^ ((tc & 7) << 2);
    #pragma unroll
    for (int q = 0; q < 4; ++q) av[q] = *(const float4*)&sA[(tr * 4 + q) * 128 + ka];
    #pragma unroll
    for (int q = 0; q < 4; ++q) bv[q] = *(const float4*)&sW[(tc * 4 + q) * 128 + kb];
    #pragma unroll
    for (int i2 = 0; i2 < 4; ++i2)
      #pragma unroll
      for (int j2 = 0; j2 < 4; ++j2){
        acc[i2][j2] += av[i2].x * bv[j2].x;
        acc[i2][j2] += av[i2].y * bv[j2].y;
        acc[i2][j2] += av[i2].z * bv[j2].z;
        acc[i2][j2] += av[i2].w * bv[j2].w;
      }
  }
  const float b0 = bias[c0 + tc*4], b1 = bias[c0 + tc*4 + 1],
              b2 = bias[c0 + tc*4 + 2], b3 = bias[c0 + tc*4 + 3];
  #pragma unroll
  for (int i2 = 0; i2 < 4; ++i2){
    int r = r0 + tr * 4 + i2;
    float4* xp = (float4*)&X[(size_t)r * 128 + c0 + tc * 4];
    float4 xv = *xp;
    xv.x += acc[i2][0] + b0;
    xv.y += acc[i2][1] + b1;
    xv.z += acc[i2][2] + b2;
    xv.w += acc[i2][3] + b3;
    *xp = xv;
  }
}

// ---------------------------------------------------------------- fused FFN block + residual
__global__ __launch_bounds__(256, 2) void k_ffn(float* __restrict__ X,
    const float* __restrict__ lg, const float* __restrict__ lb,
    const float* __restrict__ W1, const float* __restrict__ b1,
    const float* __restrict__ W2, const float* __restrict__ b2){
  __shared__ float sW1[32][132];
  __shared__ float sW2[128][36];
  __shared__ float sY[16][132];
  __shared__ float sH[16][33];
  const int t  = threadIdx.x;
  const int r0 = blockIdx.x * 16;
  {
    const float4* w1s = (const float4*)W1;    // [32][128]
    #pragma unroll
    for (int it = 0; it < 4; ++it){
      int e = it * 256 + t;                   // 0..1023
      int r = e >> 5, c4 = (e & 31) * 4;
      *(float4*)&sW1[r][c4] = w1s[e];
    }
    const float4* w2s = (const float4*)W2;    // [128][32]
    #pragma unroll
    for (int it = 0; it < 4; ++it){
      int e = it * 256 + t;
      int r = e >> 3, c4 = (e & 7) * 4;
      *(float4*)&sW2[r][c4] = w2s[e];
    }
  }
  const int row = t >> 4, p = t & 15;   // 16 rows/block, 16 threads/row
  const size_t gb = ((size_t)(r0 + row)) * 128;
  float4 xa = *(const float4*)&X[gb + p * 8];
  float4 xb = *(const float4*)&X[gb + p * 8 + 4];
  float s1 = xa.x + xa.y + xa.z + xa.w + xb.x + xb.y + xb.z + xb.w;
  float s2 = xa.x*xa.x + xa.y*xa.y + xa.z*xa.z + xa.w*xa.w
           + xb.x*xb.x + xb.y*xb.y + xb.z*xb.z + xb.w*xb.w;
  #pragma unroll
  for (int msk = 1; msk < 16; msk <<= 1){ s1 += __shfl_xor(s1, msk); s2 += __shfl_xor(s2, msk); }
  float mean = s1 * (1.f / 128.f);
  float rstd = rsqrtf(s2 * (1.f / 128.f) - mean * mean + 1e-5f);
  {
    float4 g0 = *(const float4*)&lg[p * 8], g1 = *(const float4*)&lg[p * 8 + 4];
    float4 c0 = *(const float4*)&lb[p * 8], c1 = *(const float4*)&lb[p * 8 + 4];
    float4 y0, y1;
    y0.x = (xa.x-mean)*rstd*g0.x + c0.x;  y0.y = (xa.y-mean)*rstd*g0.y + c0.y;
    y0.z = (xa.z-mean)*rstd*g0.z + c0.z;  y0.w = (xa.w-mean)*rstd*g0.w + c0.w;
    y1.x = (xb.x-mean)*rstd*g1.x + c1.x;  y1.y = (xb.y-mean)*rstd*g1.y + c1.y;
    y1.z = (xb.z-mean)*rstd*g1.z + c1.z;  y1.w = (xb.w-mean)*rstd*g1.w + c1.w;
    *(float4*)&sY[row][p * 8]     = y0;
    *(float4*)&sY[row][p * 8 + 4] = y1;
  }
  __syncthreads();
  #pragma unroll
  for (int cc = 0; cc < 2; ++cc){
    int c = p + cc * 16;
    float acc = b1[c];
    #pragma unroll
    for (int k = 0; k < 128; ++k) acc += sY[row][k] * sW1[c][k];
    sH[row][c] = 0.5f * acc * (1.0f + erff(acc * 0.70710678118654752f));
  }
  __syncthreads();
  #pragma unroll
  for (int u = 0; u < 8; ++u){
    int c = p + u * 16;
    float acc = b2[c];
    #pragma unroll
    for (int k = 0; k < 32; ++k) acc += sH[row][k] * sW2[c][k];
    X[gb + c] += acc;
  }
}

// ---------------------------------------------------------------- final LN
__global__ __launch_bounds__(256) void k_final(const float* __restrict__ X,
    const float* __restrict__ g, const float* __restrict__ b, float* __restrict__ out){
  const int t = threadIdx.x;
  const int row = blockIdx.x * 64 + (t >> 2), p = t & 3;
  const float* src = X + (size_t)row * 128 + p * 32;
  float4 v[8];
  float s1 = 0.f, s2 = 0.f;
  #pragma unroll
  for (int u = 0; u < 8; ++u){
    v[u] = *(const float4*)&src[u * 4];
    s1 += v[u].x + v[u].y + v[u].z + v[u].w;
    s2 += v[u].x*v[u].x + v[u].y*v[u].y + v[u].z*v[u].z + v[u].w*v[u].w;
  }
  s1 += __shfl_xor(s1, 1); s2 += __shfl_xor(s2, 1);
  s1 += __shfl_xor(s1, 2); s2 += __shfl_xor(s2, 2);
  float mean = s1 * (1.f / 128.f);
  float rstd = rsqrtf(s2 * (1.f / 128.f) - mean * mean + 1e-5f);
  float* dst = out + (size_t)row * 128 + p * 32;
  #pragma unroll
  for (int u = 0; u < 8; ++u){
    int c = p * 32 + u * 4;
    float4 gv = *(const float4*)&g[c];
    float4 bv = *(const float4*)&b[c];
    float4 o;
    o.x = (v[u].x - mean) * rstd * gv.x + bv.x;
    o.y = (v[u].y - mean) * rstd * gv.y + bv.y;
    o.z = (v[u].z - mean) * rstd * gv.z + bv.z;
    o.w = (v[u].w - mean) * rstd * gv.w + bv.w;
    *(float4*)&dst[u * 4] = o;
  }
}

// ---------------------------------------------------------------- launch
extern "C" void kernel_launch(void* const* d_in, const int* in_sizes, int n_in,
                              void* d_out, int out_size, void* d_ws, size_t ws_size,
                              hipStream_t stream){
  (void)in_sizes; (void)n_in; (void)out_size; (void)ws_size;
  const float* node_embedded   = (const float*)d_in[0];
  const float* heights         = (const float*)d_in[1];
  const int*   rel_pos_mat     = (const int*)d_in[2];
  const float* tree_attn_bias  = (const float*)d_in[3];
  const float* index_attn_bias = (const float*)d_in[4];
  const float* super_node_emb  = (const float*)d_in[5];
  const float* rel_pos_emb     = (const float*)d_in[6];
  const float* super_dist      = (const float*)d_in[7];
  const float* attn_out_w      = (const float*)d_in[8];
  const float* attn_out_b      = (const float*)d_in[9];
  const float* ffn_ln_g        = (const float*)d_in[10];
  const float* ffn_ln_b        = (const float*)d_in[11];
  const float* ffn_w1          = (const float*)d_in[12];
  const float* ffn_b1          = (const float*)d_in[13];
  const float* ffn_w2          = (const float*)d_in[14];
  const float* ffn_b2          = (const float*)d_in[15];
  const float* final_ln_g      = (const float*)d_in[16];
  const float* final_ln_b      = (const float*)d_in[17];
  const float* e1_ln_g = (const float*)d_in[18];
  const float* e1_ln_b = (const float*)d_in[19];
  const float* e1_wq   = (const float*)d_in[20];
  const float* e1_bq   = (const float*)d_in[21];
  const float* e1_wk   = (const float*)d_in[22];
  const float* e1_bk   = (const float*)d_in[23];
  const float* e1_wv   = (const float*)d_in[24];
  const float* e1_bv   = (const float*)d_in[25];
  const float* e2_ln_g = (const float*)d_in[26];
  const float* e2_ln_b = (const float*)d_in[27];
  const float* e2_wq   = (const float*)d_in[28];
  const float* e2_bq   = (const float*)d_in[29];
  const float* e2_wk   = (const float*)d_in[30];
  const float* e2_bk   = (const float*)d_in[31];
  const float* e2_wv   = (const float*)d_in[32];
  const float* e2_bv   = (const float*)d_in[33];

  float* ws = (float*)d_ws;
  const size_t SZX = 8388608, SZH = 4194304;
  float* X  = ws;
  float* Q1 = X  + SZX;
  float* K1 = Q1 + SZH;
  float* V1 = K1 + SZH;
  float* Q2 = V1 + SZH;
  float* K2 = Q2 + SZH;
  float* V2 = K2 + SZH;
  float* YC = V2 + SZH;

  k_build_x<<<8192, 256, 0, stream>>>((const float4*)node_embedded, (const float4*)heights,
                                      (const float4*)super_node_emb, (float4*)X);
  for (int l = 0; l < 4; ++l){
    QkvArgs A;
    A.x = X;
    A.ln_g[0] = e1_ln_g + l * 128;  A.ln_b[0] = e1_ln_b + l * 128;
    A.ln_g[1] = e2_ln_g + l * 128;  A.ln_b[1] = e2_ln_b + l * 128;
    A.w[0] = e1_wq + (size_t)l * 8192;  A.wb[0] = e1_bq + l * 64;
    A.w[1] = e1_wk + (size_t)l * 8192;  A.wb[1] = e1_bk + l * 64;
    A.w[2] = e1_wv + (size_t)l * 8192;  A.wb[2] = e1_bv + l * 64;
    A.w[3] = e2_wq + (size_t)l * 8192;  A.wb[3] = e2_bq + l * 64;
    A.w[4] = e2_wk + (size_t)l * 8192;  A.wb[4] = e2_bk + l * 64;
    A.w[5] = e2_wv + (size_t)l * 8192;  A.wb[5] = e2_bv + l * 64;
    A.out[0] = Q1; A.out[1] = K1; A.out[2] = V1;
    A.out[3] = Q2; A.out[4] = K2; A.out[5] = V2;
    k_qkv<<<dim3(2048, 2), 256, 0, stream>>>(A);
    k_attn1<<<dim3(512, 4), 512, 0, stream>>>(Q1, K1, V1, index_attn_bias, YC);
    k_attn2<<<dim3(512, 4), 512, 0, stream>>>(Q2, K2, V2, tree_attn_bias, rel_pos_mat,
                                              rel_pos_emb, super_dist, YC);
    k_attn_out<<<dim3(1024, 2), 256, 0, stream>>>(YC, attn_out_w, attn_out_b, X);
    k_ffn<<<4096, 256, 0, stream>>>(X, ffn_ln_g, ffn_ln_b, ffn_w1, ffn_b1, ffn_w2, ffn_b2);
  }
  k_final<<<1024, 256, 0, stream>>>(X, final_ln_g, final_ln_b, (float*)d_out);
}

// Round 10
// 1776.394 us; speedup vs baseline: 1.1998x; 1.1998x over previous
//
#include <hip/hip_runtime.h>
#include <cstdint>
#include <cstddef>

// B=4, I=128, N=128 (127+super), D=128, H=4, DK=16, L=4, FFN=32
// ws layout (floats): X[8388608] Q1 K1 V1 Q2 K2 V2 [4194304 each] YC[8388608]
// All Q/K/V tensors share layout [(b*128+i)*4 + h][n*16 + u] (round-2 fix).
// Attention (round-9 fix): ALL 4 HEADS per block -- each seq's 64KB bias tile
// (iab / tree+mat) is fetched by exactly ONE block, killing the 4x per-XCD
// L2-miss duplication (round-9 profile: FETCH 661MB, 43% HBM-peak, dur 198us).
// 4 lanes per row, 32 scores/thread, quad shfl reductions; sK/sV[h][128][16]
// with col^((j>>5)<<2) XOR swizzle (4 j's per wave instr -> disjoint groups).
// k_qkv: encoder-split + per-buffer swizzle (round-6).

__device__ __forceinline__ int swz (int r, int c){ return c ^ (((r >> 2) & 7) << 2); }
__device__ __forceinline__ int swzA(int r, int c){ return c ^ ((r & 7) << 2); }

// ---------------------------------------------------------------- build x0
__global__ __launch_bounds__(256) void k_build_x(const float4* __restrict__ ne,
    const float4* __restrict__ hts, const float4* __restrict__ sup,
    float4* __restrict__ X){
  int idx = blockIdx.x * 256 + threadIdx.x;      // 2097152 float4s
  int d4 = idx & 31;
  int n  = (idx >> 5) & 127;
  int bi = idx >> 12;
  float4 v;
  if (n == 0){
    v = sup[d4];
  } else {
    size_t s = ((size_t)bi * 127 + (n - 1)) * 32 + d4;
    float4 a = ne[s], h = hts[s];
    v.x = a.x + h.x; v.y = a.y + h.y; v.z = a.z + h.z; v.w = a.w + h.w;
  }
  X[idx] = v;
}

// ---------------------------------------------------------------- LN + QKV (one encoder per block.y)
struct QkvArgs {
  const float* x;
  const float* ln_g[2]; const float* ln_b[2];
  const float* w[6];  const float* wb[6];
  float* out[6];   // all: [(b*128+i)*4 + h][n*16 + u]
};

__global__ __launch_bounds__(256, 3) void k_qkv(QkvArgs A){
  __shared__ float sY[32 * 128];    // this encoder's LN'd rows (swzA layout)
  __shared__ float sW[64 * 128];    // current W tile (swz layout)
  const int r0  = blockIdx.x * 32;
  const int enc = blockIdx.y;       // 0 or 1
  const int t   = threadIdx.x;
  // ---- stage raw X tile (32 rows x 128)
  {
    const float4* xs = (const float4*)(A.x + (size_t)r0 * 128);
    #pragma unroll
    for (int it = 0; it < 4; ++it){
      int el = it * 256 + t;                 // 0..1023
      int rr = el >> 5, c4 = (el & 31) * 4;
      *(float4*)&sY[rr * 128 + swzA(rr, c4)] = xs[el];
    }
  }
  __syncthreads();
  // ---- LN: 8 threads per row, contiguous 16-float slices
  const int row = t >> 3, part = t & 7;
  float s1 = 0.f, s2 = 0.f;
  float4 xv[4];
  #pragma unroll
  for (int q = 0; q < 4; ++q){
    int c4 = part * 16 + q * 4;
    xv[q] = *(const float4*)&sY[row * 128 + swzA(row, c4)];
    s1 += xv[q].x + xv[q].y + xv[q].z + xv[q].w;
    s2 += xv[q].x*xv[q].x + xv[q].y*xv[q].y + xv[q].z*xv[q].z + xv[q].w*xv[q].w;
  }
  s1 += __shfl_xor(s1, 1); s2 += __shfl_xor(s2, 1);
  s1 += __shfl_xor(s1, 2); s2 += __shfl_xor(s2, 2);
  s1 += __shfl_xor(s1, 4); s2 += __shfl_xor(s2, 4);
  float mean = s1 * (1.f / 128.f);
  float rstd = rsqrtf(s2 * (1.f / 128.f) - mean * mean + 1e-5f);
  {
    const float* lg = A.ln_g[enc];
    const float* lb = A.ln_b[enc];
    #pragma unroll
    for (int q = 0; q < 4; ++q){
      int cc = part * 16 + q * 4;
      int a  = row * 128 + swzA(row, cc);
      float4 gv = *(const float4*)&lg[cc];
      float4 bv = *(const float4*)&lb[cc];
      float4 y;
      y.x = (xv[q].x - mean) * rstd * gv.x + bv.x;
      y.y = (xv[q].y - mean) * rstd * gv.y + bv.y;
      y.z = (xv[q].z - mean) * rstd * gv.z + bv.z;
      y.w = (xv[q].w - mean) * rstd * gv.w + bv.w;
      *(float4*)&sY[a] = y;
    }
  }
  // ---- 3 GEMMs: 32x64x128 each; thread = 2 rows x 4 cols
  const int tc = t & 15, tr = t >> 4;
  const int kb_x  = (tc & 7) << 2;           // sW swizzle: W rows tc*4..+3 share (r>>2)
  const int ra0 = tr * 2, ra1 = tr * 2 + 1;
  const int ka_x0 = (ra0 & 7) << 2;          // sY swizzle: per-row -> A-reads conflict-free
  const int ka_x1 = (ra1 & 7) << 2;
  for (int g3 = 0; g3 < 3; ++g3){
    const int g = enc * 3 + g3;
    __syncthreads();                          // prev compute / LN done before sW overwrite
    {
      const float4* wsrc = (const float4*)A.w[g];
      #pragma unroll
      for (int it = 0; it < 8; ++it){
        int el = it * 256 + t;                // 0..2047
        int rr = el >> 5, c4 = (el & 31) * 4;
        *(float4*)&sW[rr * 128 + swz(rr, c4)] = wsrc[el];
      }
    }
    __syncthreads();
    float acc[2][4] = {};
    #pragma unroll
    for (int k = 0; k < 128; k += 4){
      float4 av[2], bv[4];
      av[0] = *(const float4*)&sY[ra0 * 128 + (k ^ ka_x0)];
      av[1] = *(const float4*)&sY[ra1 * 128 + (k ^ ka_x1)];
      int kb = k ^ kb_x;
      #pragma unroll
      for (int q = 0; q < 4; ++q) bv[q] = *(const float4*)&sW[(tc * 4 + q) * 128 + kb];
      #pragma unroll
      for (int i2 = 0; i2 < 2; ++i2)
        #pragma unroll
        for (int j2 = 0; j2 < 4; ++j2){
          acc[i2][j2] += av[i2].x * bv[j2].x;
          acc[i2][j2] += av[i2].y * bv[j2].y;
          acc[i2][j2] += av[i2].z * bv[j2].z;
          acc[i2][j2] += av[i2].w * bv[j2].w;
        }
    }
    const float scale = (g3 == 0) ? 0.25f : 1.0f;   // SCALE = DK^-0.5 on Q only
    const float* wb = A.wb[g];
    const float b0 = wb[tc*4], b1 = wb[tc*4+1], b2 = wb[tc*4+2], b3 = wb[tc*4+3];
    float* outp = A.out[g];
    const int h_ = tc >> 2, u_ = (tc & 3) * 4;
    #pragma unroll
    for (int i2 = 0; i2 < 2; ++i2){
      int gr = r0 + tr * 2 + i2;              // ((b*128+i)*128+n)
      size_t off = ((size_t)((gr >> 7) * 4 + h_)) * 2048 + (gr & 127) * 16 + u_;
      float4 o;
      o.x = (acc[i2][0] + b0) * scale;
      o.y = (acc[i2][1] + b1) * scale;
      o.z = (acc[i2][2] + b2) * scale;
      o.w = (acc[i2][3] + b3) * scale;
      *(float4*)&outp[off] = o;
    }
  }
}

// ---------------------------------------------------------------- attention, index stream (enc1)
// One block per seq, ALL 4 heads; 4 lanes per row (i = t>>2, qd = t&3).
__global__ __launch_bounds__(512) void k_attn1(const float* __restrict__ Q,
    const float* __restrict__ K, const float* __restrict__ V,
    const float* __restrict__ iab, float* __restrict__ YC){
  __shared__ float sK[4][128][16];
  __shared__ float sV[4][128][16];
  const int seq = blockIdx.x;    // b*128 + n
  const int t   = threadIdx.x;
  const int i   = t >> 2, qd = t & 3;
  const int b_ = seq >> 7, n_ = seq & 127;
  const int swc = (qd * 4) ^ ((i >> 5) << 2);
  #pragma unroll
  for (int h = 0; h < 4; ++h){
    const size_t rb = ((size_t)((b_ * 128 + i) * 4 + h)) * 2048 + n_ * 16;
    *(float4*)&sK[h][i][swc] = *(const float4*)&K[rb + qd * 4];
    *(float4*)&sV[h][i][swc] = *(const float4*)&V[rb + qd * 4];
  }
  __syncthreads();
  const float4* brow = (const float4*)(iab + (size_t)seq * 16384 + (size_t)i * 128 + qd * 32);
  const int jsw = qd << 2;                   // (j>>5)<<2 for j = qd*32+jj
  #pragma unroll 1
  for (int h = 0; h < 4; ++h){
    const size_t rb = ((size_t)((b_ * 128 + i) * 4 + h)) * 2048 + n_ * 16;
    float q[16];
    #pragma unroll
    for (int u = 0; u < 4; ++u){
      float4 v = *(const float4*)&Q[rb + u * 4];
      q[u*4+0] = v.x; q[u*4+1] = v.y; q[u*4+2] = v.z; q[u*4+3] = v.w;
    }
    float s[32];
    #pragma unroll
    for (int j8 = 0; j8 < 8; ++j8){
      float4 bv4 = brow[j8];
      float bb[4] = {bv4.x, bv4.y, bv4.z, bv4.w};
      #pragma unroll
      for (int u = 0; u < 4; ++u){
        int jj = j8 * 4 + u;
        int j  = qd * 32 + jj;
        float acc = bb[u];
        #pragma unroll
        for (int u4 = 0; u4 < 4; ++u4){
          float4 kv = *(const float4*)&sK[h][j][(u4 * 4) ^ jsw];
          acc += q[u4*4+0]*kv.x + q[u4*4+1]*kv.y + q[u4*4+2]*kv.z + q[u4*4+3]*kv.w;
        }
        s[jj] = acc;
      }
    }
    float m = -1e30f;
    #pragma unroll
    for (int jj = 0; jj < 32; ++jj) m = fmaxf(m, s[jj]);
    m = fmaxf(m, __shfl_xor(m, 1));
    m = fmaxf(m, __shfl_xor(m, 2));
    float sum = 0.f;
    #pragma unroll
    for (int jj = 0; jj < 32; ++jj){ float ev = __expf(s[jj] - m); s[jj] = ev; sum += ev; }
    sum += __shfl_xor(sum, 1);
    sum += __shfl_xor(sum, 2);
    float inv = 1.f / sum;
    float o[16] = {};
    #pragma unroll
    for (int jj = 0; jj < 32; ++jj){
      int j = qd * 32 + jj;
      float p = s[jj];
      #pragma unroll
      for (int u4 = 0; u4 < 4; ++u4){
        float4 vv = *(const float4*)&sV[h][j][(u4 * 4) ^ jsw];
        o[u4*4+0] += p * vv.x; o[u4*4+1] += p * vv.y;
        o[u4*4+2] += p * vv.z; o[u4*4+3] += p * vv.w;
      }
    }
    #pragma unroll
    for (int e = 0; e < 16; ++e){
      o[e] += __shfl_xor(o[e], 1);
      o[e] += __shfl_xor(o[e], 2);
    }
    // y1 -> YC[b][i][n][h*16 + qd*4 ..]  (channels 0..63)
    size_t off = (((size_t)(b_ * 128 + i)) * 128 + n_) * 128 + h * 16 + qd * 4;
    float4 v;
    v.x = o[qd*4+0]*inv; v.y = o[qd*4+1]*inv; v.z = o[qd*4+2]*inv; v.w = o[qd*4+3]*inv;
    *(float4*)&YC[off] = v;
  }
}

// ---------------------------------------------------------------- attention, node stream (enc2)
__global__ __launch_bounds__(512) void k_attn2(const float* __restrict__ Q,
    const float* __restrict__ K, const float* __restrict__ V,
    const float* __restrict__ tree, const int* __restrict__ mat,
    const float* __restrict__ relemb, const float* __restrict__ sdist,
    float* __restrict__ YC){
  __shared__ float sK[4][128][16];
  __shared__ float sV[4][128][16];
  __shared__ float srel[768];          // [192][4]
  const int seq = blockIdx.x;    // b*128 + i (index)
  const int t   = threadIdx.x;
  const int i   = t >> 2, qd = t & 3;  // i = node row
  const int swc = (qd * 4) ^ ((i >> 5) << 2);
  #pragma unroll
  for (int h = 0; h < 4; ++h){
    const size_t bh = ((size_t)(seq * 4 + h)) * 2048;
    *(float4*)&sK[h][i][swc] = *(const float4*)&K[bh + i * 16 + qd * 4];
    *(float4*)&sV[h][i][swc] = *(const float4*)&V[bh + i * 16 + qd * 4];
  }
  for (int u = t; u < 768; u += 512) srel[u] = relemb[u];
  __syncthreads();
  const float4* trow = (const float4*)(tree + (size_t)seq * 16384 + (size_t)i * 128 + qd * 32);
  const int4*   mrow = (const int4*)(mat + (size_t)seq * 16384 + (size_t)i * 128 + qd * 32);
  const int jsw = qd << 2;
  #pragma unroll 1
  for (int h = 0; h < 4; ++h){
    const size_t bh = ((size_t)(seq * 4 + h)) * 2048;
    const float tsup = sdist[h];
    float q[16];
    #pragma unroll
    for (int u = 0; u < 4; ++u){
      float4 v = *(const float4*)&Q[bh + i * 16 + u * 4];
      q[u*4+0] = v.x; q[u*4+1] = v.y; q[u*4+2] = v.z; q[u*4+3] = v.w;
    }
    float s[32];
    #pragma unroll
    for (int j8 = 0; j8 < 8; ++j8){
      float4 tv = trow[j8];
      int4  mv  = mrow[j8];
      float bb[4];
      bb[0] = tv.x + srel[mv.x * 4 + h];
      bb[1] = tv.y + srel[mv.y * 4 + h];
      bb[2] = tv.z + srel[mv.z * 4 + h];
      bb[3] = tv.w + srel[mv.w * 4 + h];
      #pragma unroll
      for (int u = 0; u < 4; ++u){
        int jj = j8 * 4 + u;
        int j  = qd * 32 + jj;
        float acc = bb[u];
        if (i == 0) acc += tsup;               // tab[:, :, 0, :] += t
        else if (j == 0) acc += tsup;          // tab[:, :, 1:, 0] += t
        #pragma unroll
        for (int u4 = 0; u4 < 4; ++u4){
          float4 kv = *(const float4*)&sK[h][j][(u4 * 4) ^ jsw];
          acc += q[u4*4+0]*kv.x + q[u4*4+1]*kv.y + q[u4*4+2]*kv.z + q[u4*4+3]*kv.w;
        }
        s[jj] = acc;
      }
    }
    float m = -1e30f;
    #pragma unroll
    for (int jj = 0; jj < 32; ++jj) m = fmaxf(m, s[jj]);
    m = fmaxf(m, __shfl_xor(m, 1));
    m = fmaxf(m, __shfl_xor(m, 2));
    float sum = 0.f;
    #pragma unroll
    for (int jj = 0; jj < 32; ++jj){ float ev = __expf(s[jj] - m); s[jj] = ev; sum += ev; }
    sum += __shfl_xor(sum, 1);
    sum += __shfl_xor(sum, 2);
    float inv = 1.f / sum;
    float o[16] = {};
    #pragma unroll
    for (int jj = 0; jj < 32; ++jj){
      int j = qd * 32 + jj;
      float p = s[jj];
      #pragma unroll
      for (int u4 = 0; u4 < 4; ++u4){
        float4 vv = *(const float4*)&sV[h][j][(u4 * 4) ^ jsw];
        o[u4*4+0] += p * vv.x; o[u4*4+1] += p * vv.y;
        o[u4*4+2] += p * vv.z; o[u4*4+3] += p * vv.w;
      }
    }
    #pragma unroll
    for (int e = 0; e < 16; ++e){
      o[e] += __shfl_xor(o[e], 1);
      o[e] += __shfl_xor(o[e], 2);
    }
    // y2 -> YC[b][i_index][n][64 + h*16 + qd*4 ..]
    size_t off = (((size_t)seq) * 128 + i) * 128 + 64 + h * 16 + qd * 4;
    float4 v;
    v.x = o[qd*4+0]*inv; v.y = o[qd*4+1]*inv; v.z = o[qd*4+2]*inv; v.w = o[qd*4+3]*inv;
    *(float4*)&YC[off] = v;
  }
}

// ---------------------------------------------------------------- attn out-proj + residual
__global__ __launch_bounds__(256, 2) void k_attn_out(const float* __restrict__ YC,
    const float* __restrict__ W, const float* __restrict__ bias, float* __restrict__ X){
  __shared__ float sA[64 * 128];
  __shared__ float sW[64 * 128];
  const int r0 = blockIdx.x * 64, c0 = blockIdx.y * 64;
  const int t  = threadIdx.x;
  {
    const float4* as   = (const float4*)(YC + (size_t)r0 * 128);
    const float4* wsrc = (const float4*)(W + (size_t)c0 * 128);
    #pragma unroll
    for (int it = 0; it < 8; ++it){
      int e  = it * 256 + t;
      int rr = e >> 5, c4 = (e & 31) * 4;
      int cs = swz(rr, c4);
      *(float4*)&sA[rr * 128 + cs] = as[e];
      *(float4*)&sW[rr * 128 + cs] = wsrc[e];
    }
  }
  __syncthreads();
  const int tc = t & 15, tr = t >> 4;
  float acc[4][4] = {};
  #pragma unroll
  for (int k = 0; k < 128; k += 4){
    float4 av[4], bv[4];
    int ka = k ^ ((tr & 7) << 2);
    int kb = k ^ ((tc & 7) << 2);
    #pragma unroll
    for (int q = 0; q < 4; ++q) av[q] = *(const float4*)&sA[(tr * 4 + q) * 128 + ka];
    #pragma unroll
    for (int q = 0; q < 4; ++q) bv[q] = *(const float4*)&sW[(tc * 4 + q) * 128 + kb];
    #pragma unroll
    for (int i2 = 0; i2 < 4; ++i2)
      #pragma unroll
      for (int j2 = 0; j2 < 4; ++j2){
        acc[i2][j2] += av[i2].x * bv[j2].x;
        acc[i2][j2] += av[i2].y * bv[j2].y;
        acc[i2][j2] += av[i2].z * bv[j2].z;
        acc[i2][j2] += av[i2].w * bv[j2].w;
      }
  }
  const float b0 = bias[c0 + tc*4], b1 = bias[c0 + tc*4 + 1],
              b2 = bias[c0 + tc*4 + 2], b3 = bias[c0 + tc*4 + 3];
  #pragma unroll
  for (int i2 = 0; i2 < 4; ++i2){
    int r = r0 + tr * 4 + i2;
    float4* xp = (float4*)&X[(size_t)r * 128 + c0 + tc * 4];
    float4 xv = *xp;
    xv.x += acc[i2][0] + b0;
    xv.y += acc[i2][1] + b1;
    xv.z += acc[i2][2] + b2;
    xv.w += acc[i2][3] + b3;
    *xp = xv;
  }
}

// ---------------------------------------------------------------- fused FFN block + residual
__global__ __launch_bounds__(256, 2) void k_ffn(float* __restrict__ X,
    const float* __restrict__ lg, const float* __restrict__ lb,
    const float* __restrict__ W1, const float* __restrict__ b1,
    const float* __restrict__ W2, const float* __restrict__ b2){
  __shared__ float sW1[32][132];
  __shared__ float sW2[128][36];
  __shared__ float sY[16][132];
  __shared__ float sH[16][33];
  const int t  = threadIdx.x;
  const int r0 = blockIdx.x * 16;
  {
    const float4* w1s = (const float4*)W1;    // [32][128]
    #pragma unroll
    for (int it = 0; it < 4; ++it){
      int e = it * 256 + t;                   // 0..1023
      int r = e >> 5, c4 = (e & 31) * 4;
      *(float4*)&sW1[r][c4] = w1s[e];
    }
    const float4* w2s = (const float4*)W2;    // [128][32]
    #pragma unroll
    for (int it = 0; it < 4; ++it){
      int e = it * 256 + t;
      int r = e >> 3, c4 = (e & 7) * 4;
      *(float4*)&sW2[r][c4] = w2s[e];
    }
  }
  const int row = t >> 4, p = t & 15;   // 16 rows/block, 16 threads/row
  const size_t gb = ((size_t)(r0 + row)) * 128;
  float4 xa = *(const float4*)&X[gb + p * 8];
  float4 xb = *(const float4*)&X[gb + p * 8 + 4];
  float s1 = xa.x + xa.y + xa.z + xa.w + xb.x + xb.y + xb.z + xb.w;
  float s2 = xa.x*xa.x + xa.y*xa.y + xa.z*xa.z + xa.w*xa.w
           + xb.x*xb.x + xb.y*xb.y + xb.z*xb.z + xb.w*xb.w;
  #pragma unroll
  for (int msk = 1; msk < 16; msk <<= 1){ s1 += __shfl_xor(s1, msk); s2 += __shfl_xor(s2, msk); }
  float mean = s1 * (1.f / 128.f);
  float rstd = rsqrtf(s2 * (1.f / 128.f) - mean * mean + 1e-5f);
  {
    float4 g0 = *(const float4*)&lg[p * 8], g1 = *(const float4*)&lg[p * 8 + 4];
    float4 c0 = *(const float4*)&lb[p * 8], c1 = *(const float4*)&lb[p * 8 + 4];
    float4 y0, y1;
    y0.x = (xa.x-mean)*rstd*g0.x + c0.x;  y0.y = (xa.y-mean)*rstd*g0.y + c0.y;
    y0.z = (xa.z-mean)*rstd*g0.z + c0.z;  y0.w = (xa.w-mean)*rstd*g0.w + c0.w;
    y1.x = (xb.x-mean)*rstd*g1.x + c1.x;  y1.y = (xb.y-mean)*rstd*g1.y + c1.y;
    y1.z = (xb.z-mean)*rstd*g1.z + c1.z;  y1.w = (xb.w-mean)*rstd*g1.w + c1.w;
    *(float4*)&sY[row][p * 8]     = y0;
    *(float4*)&sY[row][p * 8 + 4] = y1;
  }
  __syncthreads();
  #pragma unroll
  for (int cc = 0; cc < 2; ++cc){
    int c = p + cc * 16;
    float acc = b1[c];
    #pragma unroll
    for (int k = 0; k < 128; ++k) acc += sY[row][k] * sW1[c][k];
    sH[row][c] = 0.5f * acc * (1.0f + erff(acc * 0.70710678118654752f));
  }
  __syncthreads();
  #pragma unroll
  for (int u = 0; u < 8; ++u){
    int c = p + u * 16;
    float acc = b2[c];
    #pragma unroll
    for (int k = 0; k < 32; ++k) acc += sH[row][k] * sW2[c][k];
    X[gb + c] += acc;
  }
}

// ---------------------------------------------------------------- final LN
__global__ __launch_bounds__(256) void k_final(const float* __restrict__ X,
    const float* __restrict__ g, const float* __restrict__ b, float* __restrict__ out){
  const int t = threadIdx.x;
  const int row = blockIdx.x * 64 + (t >> 2), p = t & 3;
  const float* src = X + (size_t)row * 128 + p * 32;
  float4 v[8];
  float s1 = 0.f, s2 = 0.f;
  #pragma unroll
  for (int u = 0; u < 8; ++u){
    v[u] = *(const float4*)&src[u * 4];
    s1 += v[u].x + v[u].y + v[u].z + v[u].w;
    s2 += v[u].x*v[u].x + v[u].y*v[u].y + v[u].z*v[u].z + v[u].w*v[u].w;
  }
  s1 += __shfl_xor(s1, 1); s2 += __shfl_xor(s2, 1);
  s1 += __shfl_xor(s1, 2); s2 += __shfl_xor(s2, 2);
  float mean = s1 * (1.f / 128.f);
  float rstd = rsqrtf(s2 * (1.f / 128.f) - mean * mean + 1e-5f);
  float* dst = out + (size_t)row * 128 + p * 32;
  #pragma unroll
  for (int u = 0; u < 8; ++u){
    int c = p * 32 + u * 4;
    float4 gv = *(const float4*)&g[c];
    float4 bv = *(const float4*)&b[c];
    float4 o;
    o.x = (v[u].x - mean) * rstd * gv.x + bv.x;
    o.y = (v[u].y - mean) * rstd * gv.y + bv.y;
    o.z = (v[u].z - mean) * rstd * gv.z + bv.z;
    o.w = (v[u].w - mean) * rstd * gv.w + bv.w;
    *(float4*)&dst[u * 4] = o;
  }
}

// ---------------------------------------------------------------- launch
extern "C" void kernel_launch(void* const* d_in, const int* in_sizes, int n_in,
                              void* d_out, int out_size, void* d_ws, size_t ws_size,
                              hipStream_t stream){
  (void)in_sizes; (void)n_in; (void)out_size; (void)ws_size;
  const float* node_embedded   = (const float*)d_in[0];
  const float* heights         = (const float*)d_in[1];
  const int*   rel_pos_mat     = (const int*)d_in[2];
  const float* tree_attn_bias  = (const float*)d_in[3];
  const float* index_attn_bias = (const float*)d_in[4];
  const float* super_node_emb  = (const float*)d_in[5];
  const float* rel_pos_emb     = (const float*)d_in[6];
  const float* super_dist      = (const float*)d_in[7];
  const float* attn_out_w      = (const float*)d_in[8];
  const float* attn_out_b      = (const float*)d_in[9];
  const float* ffn_ln_g        = (const float*)d_in[10];
  const float* ffn_ln_b        = (const float*)d_in[11];
  const float* ffn_w1          = (const float*)d_in[12];
  const float* ffn_b1          = (const float*)d_in[13];
  const float* ffn_w2          = (const float*)d_in[14];
  const float* ffn_b2          = (const float*)d_in[15];
  const float* final_ln_g      = (const float*)d_in[16];
  const float* final_ln_b      = (const float*)d_in[17];
  const float* e1_ln_g = (const float*)d_in[18];
  const float* e1_ln_b = (const float*)d_in[19];
  const float* e1_wq   = (const float*)d_in[20];
  const float* e1_bq   = (const float*)d_in[21];
  const float* e1_wk   = (const float*)d_in[22];
  const float* e1_bk   = (const float*)d_in[23];
  const float* e1_wv   = (const float*)d_in[24];
  const float* e1_bv   = (const float*)d_in[25];
  const float* e2_ln_g = (const float*)d_in[26];
  const float* e2_ln_b = (const float*)d_in[27];
  const float* e2_wq   = (const float*)d_in[28];
  const float* e2_bq   = (const float*)d_in[29];
  const float* e2_wk   = (const float*)d_in[30];
  const float* e2_bk   = (const float*)d_in[31];
  const float* e2_wv   = (const float*)d_in[32];
  const float* e2_bv   = (const float*)d_in[33];

  float* ws = (float*)d_ws;
  const size_t SZX = 8388608, SZH = 4194304;
  float* X  = ws;
  float* Q1 = X  + SZX;
  float* K1 = Q1 + SZH;
  float* V1 = K1 + SZH;
  float* Q2 = V1 + SZH;
  float* K2 = Q2 + SZH;
  float* V2 = K2 + SZH;
  float* YC = V2 + SZH;

  k_build_x<<<8192, 256, 0, stream>>>((const float4*)node_embedded, (const float4*)heights,
                                      (const float4*)super_node_emb, (float4*)X);
  for (int l = 0; l < 4; ++l){
    QkvArgs A;
    A.x = X;
    A.ln_g[0] = e1_ln_g + l * 128;  A.ln_b[0] = e1_ln_b + l * 128;
    A.ln_g[1] = e2_ln_g + l * 128;  A.ln_b[1] = e2_ln_b + l * 128;
    A.w[0] = e1_wq + (size_t)l * 8192;  A.wb[0] = e1_bq + l * 64;
    A.w[1] = e1_wk + (size_t)l * 8192;  A.wb[1] = e1_bk + l * 64;
    A.w[2] = e1_wv + (size_t)l * 8192;  A.wb[2] = e1_bv + l * 64;
    A.w[3] = e2_wq + (size_t)l * 8192;  A.wb[3] = e2_bq + l * 64;
    A.w[4] = e2_wk + (size_t)l * 8192;  A.wb[4] = e2_bk + l * 64;
    A.w[5] = e2_wv + (size_t)l * 8192;  A.wb[5] = e2_bv + l * 64;
    A.out[0] = Q1; A.out[1] = K1; A.out[2] = V1;
    A.out[3] = Q2; A.out[4] = K2; A.out[5] = V2;
    k_qkv<<<dim3(2048, 2), 256, 0, stream>>>(A);
    k_attn1<<<512, 512, 0, stream>>>(Q1, K1, V1, index_attn_bias, YC);
    k_attn2<<<512, 512, 0, stream>>>(Q2, K2, V2, tree_attn_bias, rel_pos_mat,
                                     rel_pos_emb, super_dist, YC);
    k_attn_out<<<dim3(1024, 2), 256, 0, stream>>>(YC, attn_out_w, attn_out_b, X);
    k_ffn<<<4096, 256, 0, stream>>>(X, ffn_ln_g, ffn_ln_b, ffn_w1, ffn_b1, ffn_w2, ffn_b2);
  }
  k_final<<<1024, 256, 0, stream>>>(X, final_ln_g, final_ln_b, (float*)d_out);
}